// Round 1
// baseline (154.175 us; speedup 1.0000x reference)
//
#include <hip/hip_runtime.h>
#include <hip/hip_bf16.h>

// LSTM: B=4096, T=200, I=2, H=64, O=2
// grid = 256 blocks x 256 threads; block handles 16 batch rows; wave w owns
// hidden units [16w, 16w+16) via gate tiles {w, w+4, w+8, w+12}.

#define B_ 4096
#define T_ 200
#define H_ 64

typedef _Float16 half8 __attribute__((ext_vector_type(8)));
typedef float f32x4 __attribute__((ext_vector_type(4)));

__device__ __forceinline__ float fsig(float x) {
    // 1/(1+2^(-x*log2e))
    return __builtin_amdgcn_rcpf(1.0f + exp2f(-1.4426950408889634f * x));
}
__device__ __forceinline__ float ftanh(float x) {
    // 1 - 2/(2^(x*2*log2e)+1)
    return 1.0f - 2.0f * __builtin_amdgcn_rcpf(1.0f + exp2f(2.8853900817779268f * x));
}

__global__ __launch_bounds__(256) void lstm_kernel(
    const float* __restrict__ x,     // [4096][200][2]
    const float* __restrict__ W_ih,  // [256][2]
    const float* __restrict__ W_hh,  // [256][64]
    const float* __restrict__ b_ih,  // [256]
    const float* __restrict__ b_hh,  // [256]
    const float* __restrict__ W_fc,  // [2][64]
    const float* __restrict__ b_fc,  // [2]
    float* __restrict__ out)         // [4096][2]
{
    __shared__ float xs[16][400];        // x tile for 16 rows, 25.6 KB
    __shared__ _Float16 h16[2][16][72];  // double-buffered h (pad 64->72 kills b128 bank conflict)
    __shared__ float hf[16][65];         // fp32 h_last for the FC epilogue
    __shared__ float wfc[130];           // W_fc (128) + b_fc (2)

    const int tid  = threadIdx.x;
    const int lane = tid & 63;
    const int w    = tid >> 6;      // wave 0..3
    const int cidx = lane & 15;     // col-in-tile / A-row index
    const int grp  = lane >> 4;     // 0..3
    const int r0   = blockIdx.x * 16;

    // ---- stage x tile (coalesced float4) ----
    for (int i4 = tid; i4 < 1600; i4 += 256) {
        const int row = i4 / 100;          // 100 float4 per row
        const int j4  = i4 - row * 100;
        const float4 v = reinterpret_cast<const float4*>(x + (size_t)(r0 + row) * 400)[j4];
        reinterpret_cast<float4*>(&xs[row][0])[j4] = v;
    }
    // ---- zero h16 (both buffers incl. pad) ----
    for (int i = tid; i < 2 * 16 * 72 / 2; i += 256)
        reinterpret_cast<unsigned int*>(&h16[0][0][0])[i] = 0u;
    if (tid < 130) wfc[tid] = (tid < 128) ? W_fc[tid] : b_fc[tid - 128];

    // ---- load W_hh B-fragments (f16) + input-projection coeffs, held in registers ----
    // B-frag layout for mfma_f32_16x16x32_f16: lane l -> col = l&15, k = (l>>4)*8 + e
    half8 bfrag[4][2];
    float wi0[4], wi1[4], bs[4];
    const int u = w * 16 + cidx;           // hidden unit owned by this lane
    #pragma unroll
    for (int m = 0; m < 4; ++m) {          // m = gate type: 0=i,1=f,2=g,3=o (PyTorch order)
        const int g = m * 64 + u;          // gate row in W_ih/W_hh/b_*
        wi0[m] = W_ih[g * 2 + 0];
        wi1[m] = W_ih[g * 2 + 1];
        bs[m]  = b_ih[g] + b_hh[g];
        #pragma unroll
        for (int kt = 0; kt < 2; ++kt) {
            const float* p = W_hh + g * 64 + kt * 32 + grp * 8;
            const float4 lo = reinterpret_cast<const float4*>(p)[0];
            const float4 hi = reinterpret_cast<const float4*>(p)[1];
            half8 f;
            f[0] = (_Float16)lo.x; f[1] = (_Float16)lo.y;
            f[2] = (_Float16)lo.z; f[3] = (_Float16)lo.w;
            f[4] = (_Float16)hi.x; f[5] = (_Float16)hi.y;
            f[6] = (_Float16)hi.z; f[7] = (_Float16)hi.w;
            bfrag[m][kt] = f;
        }
    }

    float cst[4] = {0.f, 0.f, 0.f, 0.f};   // cell state: 4 rows x (unit u)

    __syncthreads();

    for (int t = 0; t < T_; ++t) {
        const int rd = t & 1, wr = rd ^ 1;
        // A-frag: lane l -> row = l&15, k = (l>>4)*8 + e (+32 for kt=1)
        const half8 a0 = *reinterpret_cast<const half8*>(&h16[rd][cidx][grp * 8]);
        const half8 a1 = *reinterpret_cast<const half8*>(&h16[rd][cidx][32 + grp * 8]);

        f32x4 acc[4];
        #pragma unroll
        for (int m = 0; m < 4; ++m) {
            f32x4 a = {0.f, 0.f, 0.f, 0.f};
            a = __builtin_amdgcn_mfma_f32_16x16x32_f16(a0, bfrag[m][0], a, 0, 0, 0);
            a = __builtin_amdgcn_mfma_f32_16x16x32_f16(a1, bfrag[m][1], a, 0, 0, 0);
            acc[m] = a;
        }

        float hnew[4];
        #pragma unroll
        for (int r = 0; r < 4; ++r) {
            const int row = grp * 4 + r;   // C/D: row = (l>>4)*4 + reg
            const float2 xv = *reinterpret_cast<const float2*>(&xs[row][2 * t]);
            const float ip = acc[0][r] + fmaf(xv.y, wi1[0], fmaf(xv.x, wi0[0], bs[0]));
            const float fp = acc[1][r] + fmaf(xv.y, wi1[1], fmaf(xv.x, wi0[1], bs[1]));
            const float gp = acc[2][r] + fmaf(xv.y, wi1[2], fmaf(xv.x, wi0[2], bs[2]));
            const float op = acc[3][r] + fmaf(xv.y, wi1[3], fmaf(xv.x, wi0[3], bs[3]));
            const float ig = fsig(ip);
            const float fg = fsig(fp);
            const float gg = ftanh(gp);
            const float og = fsig(op);
            const float cv = fmaf(fg, cst[r], ig * gg);
            cst[r] = cv;
            hnew[r] = og * ftanh(cv);
        }

        #pragma unroll
        for (int r = 0; r < 4; ++r) {
            const int row = grp * 4 + r;
            h16[wr][row][u] = (_Float16)hnew[r];
            if (t == T_ - 1) hf[row][u] = hnew[r];
        }
        __syncthreads();
    }

    // ---- FC epilogue: out[r][o] = sum_k W_fc[o][k] * h_last[r][k] + b_fc[o] ----
    if (tid < 32) {
        const int r = tid & 15;
        const int o = tid >> 4;
        float s = wfc[128 + o];
        #pragma unroll
        for (int k = 0; k < 64; ++k)
            s = fmaf(wfc[o * 64 + k], hf[r][k], s);
        out[(size_t)(r0 + r) * 2 + o] = s;
    }
}

extern "C" void kernel_launch(void* const* d_in, const int* in_sizes, int n_in,
                              void* d_out, int out_size, void* d_ws, size_t ws_size,
                              hipStream_t stream) {
    const float* x    = (const float*)d_in[0];
    const float* W_ih = (const float*)d_in[1];
    const float* W_hh = (const float*)d_in[2];
    const float* b_ih = (const float*)d_in[3];
    const float* b_hh = (const float*)d_in[4];
    const float* W_fc = (const float*)d_in[5];
    const float* b_fc = (const float*)d_in[6];
    float* out = (float*)d_out;

    lstm_kernel<<<B_ / 16, 256, 0, stream>>>(x, W_ih, W_hh, b_ih, b_hh, W_fc, b_fc, out);
}

// Round 2
// 129.497 us; speedup vs baseline: 1.1906x; 1.1906x over previous
//
#include <hip/hip_runtime.h>
#include <hip/hip_bf16.h>

// LSTM: B=4096, T=200, I=2, H=64, O=2
// grid = 256 blocks x 512 threads (8 waves, 2 waves/SIMD).
// Waves w and w+4 (wq = w&3) both compute the gate MFMAs for units
// [16wq, 16wq+16); they split the 4 accumulator rows for activations:
// half = w>>2 handles rows grp*4 + {2*half, 2*half+1}.

#define B_ 4096
#define T_ 200
#define H_ 64

typedef _Float16 half8 __attribute__((ext_vector_type(8)));
typedef float f32x4 __attribute__((ext_vector_type(4)));

__device__ __forceinline__ float fsig(float x) {
    // 1/(1+2^(-x*log2e))
    return __builtin_amdgcn_rcpf(1.0f + __builtin_amdgcn_exp2f(-1.4426950408889634f * x));
}
__device__ __forceinline__ float ftanh(float x) {
    // 1 - 2/(2^(x*2*log2e)+1)
    return 1.0f - 2.0f * __builtin_amdgcn_rcpf(1.0f + __builtin_amdgcn_exp2f(2.8853900817779268f * x));
}

__global__ __launch_bounds__(512) void lstm_kernel(
    const float* __restrict__ x,     // [4096][200][2]
    const float* __restrict__ W_ih,  // [256][2]
    const float* __restrict__ W_hh,  // [256][64]
    const float* __restrict__ b_ih,  // [256]
    const float* __restrict__ b_hh,  // [256]
    const float* __restrict__ W_fc,  // [2][64]
    const float* __restrict__ b_fc,  // [2]
    float* __restrict__ out)         // [4096][2]
{
    __shared__ float xs[16][400];        // x tile for 16 rows, 25.6 KB
    __shared__ _Float16 h16[2][16][72];  // double-buffered h (pad 64->72 kills b128 bank conflict)
    __shared__ float hf[16][65];         // fp32 h_last for the FC epilogue
    __shared__ float wfc[130];           // W_fc (128) + b_fc (2)

    const int tid  = threadIdx.x;
    const int lane = tid & 63;
    const int w    = tid >> 6;      // wave 0..7
    const int wq   = w & 3;         // gate-tile quadrant (units [16wq,16wq+16))
    const int half = w >> 2;        // activation row-half: rows grp*4 + 2*half + {0,1}
    const int cidx = lane & 15;     // col-in-tile / A-row index
    const int grp  = lane >> 4;     // 0..3
    const int r0   = blockIdx.x * 16;

    // ---- stage x tile (coalesced float4) ----
    for (int i4 = tid; i4 < 1600; i4 += 512) {
        const int row = i4 / 100;          // 100 float4 per row
        const int j4  = i4 - row * 100;
        const float4 v = reinterpret_cast<const float4*>(x + (size_t)(r0 + row) * 400)[j4];
        reinterpret_cast<float4*>(&xs[row][0])[j4] = v;
    }
    // ---- zero h16 (both buffers incl. pad) ----
    for (int i = tid; i < 2 * 16 * 72 / 2; i += 512)
        reinterpret_cast<unsigned int*>(&h16[0][0][0])[i] = 0u;
    if (tid < 130) wfc[tid] = (tid < 128) ? W_fc[tid] : b_fc[tid - 128];

    // ---- load W_hh B-fragments (f16) + input-projection coeffs, held in registers ----
    // B-frag layout for mfma_f32_16x16x32_f16: lane l -> col = l&15, k = (l>>4)*8 + e
    half8 bfrag[4][2];
    float wi0[4], wi1[4], bs[4];
    const int u = wq * 16 + cidx;          // hidden unit owned by this lane
    #pragma unroll
    for (int m = 0; m < 4; ++m) {          // m = gate type: 0=i,1=f,2=g,3=o (PyTorch order)
        const int g = m * 64 + u;          // gate row in W_ih/W_hh/b_*
        wi0[m] = W_ih[g * 2 + 0];
        wi1[m] = W_ih[g * 2 + 1];
        bs[m]  = b_ih[g] + b_hh[g];
        #pragma unroll
        for (int kt = 0; kt < 2; ++kt) {
            const float* p = W_hh + g * 64 + kt * 32 + grp * 8;
            const float4 lo = reinterpret_cast<const float4*>(p)[0];
            const float4 hi = reinterpret_cast<const float4*>(p)[1];
            half8 f;
            f[0] = (_Float16)lo.x; f[1] = (_Float16)lo.y;
            f[2] = (_Float16)lo.z; f[3] = (_Float16)lo.w;
            f[4] = (_Float16)hi.x; f[5] = (_Float16)hi.y;
            f[6] = (_Float16)hi.z; f[7] = (_Float16)hi.w;
            bfrag[m][kt] = f;
        }
    }

    float cst[2] = {0.f, 0.f};             // cell state: 2 rows x (unit u)

    __syncthreads();

    for (int t = 0; t < T_; ++t) {
        const int rd = t & 1, wr = rd ^ 1;
        // A-frag: lane l -> row = l&15, k = (l>>4)*8 + e (+32 for kt=1)
        const half8 a0 = *reinterpret_cast<const half8*>(&h16[rd][cidx][grp * 8]);
        const half8 a1 = *reinterpret_cast<const half8*>(&h16[rd][cidx][32 + grp * 8]);

        f32x4 acc[4];
        #pragma unroll
        for (int m = 0; m < 4; ++m) {
            f32x4 a = {0.f, 0.f, 0.f, 0.f};
            a = __builtin_amdgcn_mfma_f32_16x16x32_f16(a0, bfrag[m][0], a, 0, 0, 0);
            a = __builtin_amdgcn_mfma_f32_16x16x32_f16(a1, bfrag[m][1], a, 0, 0, 0);
            acc[m] = a;
        }

        // ---- activations on this wave's 2 rows ----
        #pragma unroll
        for (int s = 0; s < 2; ++s) {
            const int r   = 2 * half + s;  // C/D reg index
            const int row = grp * 4 + r;   // C/D: row = (l>>4)*4 + reg
            const float2 xv = *reinterpret_cast<const float2*>(&xs[row][2 * t]);
            const float ip = acc[0][r] + fmaf(xv.y, wi1[0], fmaf(xv.x, wi0[0], bs[0]));
            const float fp = acc[1][r] + fmaf(xv.y, wi1[1], fmaf(xv.x, wi0[1], bs[1]));
            const float gp = acc[2][r] + fmaf(xv.y, wi1[2], fmaf(xv.x, wi0[2], bs[2]));
            const float op = acc[3][r] + fmaf(xv.y, wi1[3], fmaf(xv.x, wi0[3], bs[3]));
            const float ig = fsig(ip);
            const float fg = fsig(fp);
            const float gg = ftanh(gp);
            const float og = fsig(op);
            const float cv = fmaf(fg, cst[s], ig * gg);
            cst[s] = cv;
            const float hv = og * ftanh(cv);
            h16[wr][row][u] = (_Float16)hv;
            if (t == T_ - 1) hf[row][u] = hv;
        }
        __syncthreads();
    }

    // ---- FC epilogue: out[r][o] = sum_k W_fc[o][k] * h_last[r][k] + b_fc[o] ----
    if (tid < 32) {
        const int r = tid & 15;
        const int o = tid >> 4;
        float s = wfc[128 + o];
        #pragma unroll
        for (int k = 0; k < 64; ++k)
            s = fmaf(wfc[o * 64 + k], hf[r][k], s);
        out[(size_t)(r0 + r) * 2 + o] = s;
    }
}

extern "C" void kernel_launch(void* const* d_in, const int* in_sizes, int n_in,
                              void* d_out, int out_size, void* d_ws, size_t ws_size,
                              hipStream_t stream) {
    const float* x    = (const float*)d_in[0];
    const float* W_ih = (const float*)d_in[1];
    const float* W_hh = (const float*)d_in[2];
    const float* b_ih = (const float*)d_in[3];
    const float* b_hh = (const float*)d_in[4];
    const float* W_fc = (const float*)d_in[5];
    const float* b_fc = (const float*)d_in[6];
    float* out = (float*)d_out;

    lstm_kernel<<<B_ / 16, 512, 0, stream>>>(x, W_ih, W_hh, b_ih, b_hh, W_fc, b_fc, out);
}

// Round 3
// 115.528 us; speedup vs baseline: 1.3345x; 1.1209x over previous
//
#include <hip/hip_runtime.h>
#include <hip/hip_bf16.h>

// LSTM: B=4096, T=200, I=2, H=64, O=2
// grid = 256 blocks x 1024 threads (16 waves, 4 waves/SIMD).
// Wave w: wq = w&3 -> unit quadrant [16wq, 16wq+16); qr = w>>2 -> row rotation.
// The 4 waves sharing a quadrant compute IDENTICAL gate MFMAs except their
// A-fragments are loaded from rows rotated by qr: A'[p] = h[(p+qr)&15].
// Hence D reg 0 (rows p = grp*4) of wave qr holds batch rows (grp*4+qr)&15 —
// all 16 rows covered across qr=0..3 with a STATIC acc index (a[0]).
// Each lane then activates exactly one (row, unit) pair: ~34 VALU + 10 trans.

#define B_ 4096
#define T_ 200

typedef _Float16 half8 __attribute__((ext_vector_type(8)));
typedef float f32x4 __attribute__((ext_vector_type(4)));

__device__ __forceinline__ float fsig(float x) {
    // 1/(1+2^(-x*log2e))
    return __builtin_amdgcn_rcpf(1.0f + __builtin_amdgcn_exp2f(-1.4426950408889634f * x));
}
__device__ __forceinline__ float ftanh(float x) {
    // 1 - 2/(2^(x*2*log2e)+1)
    return fmaf(-2.0f, __builtin_amdgcn_rcpf(1.0f + __builtin_amdgcn_exp2f(2.8853900817779268f * x)), 1.0f);
}

__global__ __launch_bounds__(1024) void lstm_kernel(
    const float* __restrict__ x,     // [4096][200][2]
    const float* __restrict__ W_ih,  // [256][2]
    const float* __restrict__ W_hh,  // [256][64]
    const float* __restrict__ b_ih,  // [256]
    const float* __restrict__ b_hh,  // [256]
    const float* __restrict__ W_fc,  // [2][64]
    const float* __restrict__ b_fc,  // [2]
    float* __restrict__ out)         // [4096][2]
{
    __shared__ float xs[16][404];        // pad 400->404: de-conflicts xv reads, keeps 16B align
    __shared__ _Float16 h16[2][16][72];  // double-buffered h (pad 64->72: conflict-free b128)
    __shared__ float wfc[130];           // W_fc (128) + b_fc (2)

    const int tid  = threadIdx.x;
    const int lane = tid & 63;
    const int w    = tid >> 6;      // 0..15
    const int wq   = w & 3;         // unit quadrant
    const int qr   = w >> 2;        // row rotation 0..3
    const int cidx = lane & 15;
    const int grp  = lane >> 4;
    const int r0   = blockIdx.x * 16;

    // ---- stage x tile (coalesced float4) ----
    for (int i4 = tid; i4 < 1600; i4 += 1024) {
        const int row = i4 / 100;          // 100 float4 per row
        const int j4  = i4 - row * 100;
        reinterpret_cast<float4*>(&xs[row][0])[j4] =
            reinterpret_cast<const float4*>(x + (size_t)(r0 + row) * 400)[j4];
    }
    // ---- zero h16 (both buffers incl. pad) ----
    for (int i = tid; i < 1152; i += 1024)
        reinterpret_cast<unsigned int*>(&h16[0][0][0])[i] = 0u;
    if (tid < 130) wfc[tid] = (tid < 128) ? W_fc[tid] : b_fc[tid - 128];

    // ---- W_hh B-fragments (f16) + input-projection coeffs, in registers ----
    // B-frag layout for mfma_f32_16x16x32_f16: lane l -> col = l&15, k = (l>>4)*8 + e
    half8 bfrag[4][2];
    float wi0[4], wi1[4], bs[4];
    const int u = wq * 16 + cidx;          // hidden unit owned by this lane
    #pragma unroll
    for (int m = 0; m < 4; ++m) {          // gate: 0=i,1=f,2=g,3=o (PyTorch order)
        const int g = m * 64 + u;
        wi0[m] = W_ih[g * 2 + 0];
        wi1[m] = W_ih[g * 2 + 1];
        bs[m]  = b_ih[g] + b_hh[g];
        #pragma unroll
        for (int kt = 0; kt < 2; ++kt) {
            const float* p = W_hh + g * 64 + kt * 32 + grp * 8;
            const float4 lo = reinterpret_cast<const float4*>(p)[0];
            const float4 hi = reinterpret_cast<const float4*>(p)[1];
            half8 f;
            f[0] = (_Float16)lo.x; f[1] = (_Float16)lo.y;
            f[2] = (_Float16)lo.z; f[3] = (_Float16)lo.w;
            f[4] = (_Float16)hi.x; f[5] = (_Float16)hi.y;
            f[6] = (_Float16)hi.z; f[7] = (_Float16)hi.w;
            bfrag[m][kt] = f;
        }
    }

    const int arow = (cidx + qr) & 15;      // rotated A-frag source row
    const int row  = (grp * 4 + qr) & 15;   // batch row this lane activates
    float cst = 0.f;                        // cell state for (row, u)

    __syncthreads();

    for (int t = 0; t < T_; ++t) {
        const int rd = t & 1;
        const _Float16* hb = &h16[rd][0][0];
        // A-frag: lane l -> A'[l&15][k=(l>>4)*8+e], A'[p] = h[(p+qr)&15]
        const half8 a0 = *reinterpret_cast<const half8*>(hb + arow * 72 + grp * 8);
        const half8 a1 = *reinterpret_cast<const half8*>(hb + arow * 72 + 32 + grp * 8);
        const float2 xv = *reinterpret_cast<const float2*>(&xs[row][2 * t]);

        float pre[4];
        #pragma unroll
        for (int m = 0; m < 4; ++m) {
            f32x4 a = {bs[m], bs[m], bs[m], bs[m]};   // bias pre-loaded into C
            a = __builtin_amdgcn_mfma_f32_16x16x32_f16(a0, bfrag[m][0], a, 0, 0, 0);
            a = __builtin_amdgcn_mfma_f32_16x16x32_f16(a1, bfrag[m][1], a, 0, 0, 0);
            pre[m] = fmaf(xv.y, wi1[m], fmaf(xv.x, wi0[m], a[0]));  // STATIC reg 0
        }

        const float ig = fsig(pre[0]);
        const float fg = fsig(pre[1]);
        const float gg = ftanh(pre[2]);
        const float og = fsig(pre[3]);
        cst = fmaf(fg, cst, ig * gg);
        const float hv = og * ftanh(cst);
        h16[rd ^ 1][row][u] = (_Float16)hv;
        __syncthreads();
    }

    // ---- FC epilogue: h_last is in h16[0] (t=199 wrote buffer 0) ----
    if (tid < 32) {
        const int r = tid & 15;
        const int o = tid >> 4;
        float s = wfc[128 + o];
        #pragma unroll
        for (int k = 0; k < 64; ++k)
            s = fmaf(wfc[o * 64 + k], (float)h16[0][r][k], s);
        out[(size_t)(r0 + r) * 2 + o] = s;
    }
}

extern "C" void kernel_launch(void* const* d_in, const int* in_sizes, int n_in,
                              void* d_out, int out_size, void* d_ws, size_t ws_size,
                              hipStream_t stream) {
    const float* x    = (const float*)d_in[0];
    const float* W_ih = (const float*)d_in[1];
    const float* W_hh = (const float*)d_in[2];
    const float* b_ih = (const float*)d_in[3];
    const float* b_hh = (const float*)d_in[4];
    const float* W_fc = (const float*)d_in[5];
    const float* b_fc = (const float*)d_in[6];
    float* out = (float*)d_out;

    lstm_kernel<<<B_ / 16, 1024, 0, stream>>>(x, W_ih, W_hh, b_ih, b_hh, W_fc, b_fc, out);
}